// Round 5
// baseline (212.865 us; speedup 1.0000x reference)
//
#include <hip/hip_runtime.h>
#include <hip/hip_bf16.h>

// MFVIConstituency: B=16, S=128, MAX_ITER=3.
// q_new[b,i,j] = s_span[b,i,j] + sum_k sigmoid(q[b,i,k]) * sp[b,i,j,k]
// sp[b,i,j,k]  = s_pair[b,i,j,k] * ( mask[b,i,j] & (k!=min(i,j)) & (k!=max(i,j))
//                                     & (mask[b,j,k]|mask[b,k,j]) )
//
// Round-5: round-4 structure (shfl-tree reduce, precomputed compact active
// lists, 3 barriers/block) + DOUBLE-BUFFERED prow to fix the round-4 race:
// reading p(it) and writing p(it+1) now touch different buffers, so one
// barrier per iteration is sufficient and correct.

#define S 128
#define MB_STRIDE 132     // mask byte tile: transposed byte reads conflict-free

static __device__ __forceinline__ float fsig(float x) {
    return __builtin_amdgcn_rcpf(1.0f + __expf(-x));
}

// -------- pre-pack per batch: span bitmasks + per-(b,i) compact row lists --------
__global__ __launch_bounds__(256, 2) void pack_masks(
    const int* __restrict__ mask,
    unsigned* __restrict__ spanw,        // [B*S*4]  bit k of row j: m[j,k]|m[k,j]
    unsigned char* __restrict__ actg,    // [B*S*S]  compact active-j list per (b,i)
    int* __restrict__ nactg)             // [B*S]
{
    __shared__ unsigned char mb[S * MB_STRIDE];   // 16896 B
    const int t = threadIdx.x, b = blockIdx.x;
    const int* mrow = mask + (long long)b * (S * S);
    #pragma unroll
    for (int s2 = 0; s2 < 16; ++s2) {
        int f4 = t + 256 * s2;            // int4 index 0..4095
        int j  = f4 >> 5;
        int k0 = (f4 & 31) * 4;
        int4 v = *(const int4*)(mrow + f4 * 4);
        unsigned packed = (v.x ? 1u : 0u)
                        | ((v.y ? 1u : 0u) << 8)
                        | ((v.z ? 1u : 0u) << 16)
                        | ((v.w ? 1u : 0u) << 24);
        *(unsigned*)(mb + j * MB_STRIDE + k0) = packed;
    }
    __syncthreads();

    // span bits
    #pragma unroll
    for (int r = 0; r < 2; ++r) {
        int task = t * 2 + r;             // (j, w)
        int j = task >> 2, w = task & 3;
        unsigned sbits = 0;
        #pragma unroll
        for (int c = 0; c < 32; ++c) {
            int k = w * 32 + c;
            sbits |= ((mb[j * MB_STRIDE + k] | mb[k * MB_STRIDE + j]) ? 1u : 0u) << c;
        }
        spanw[(b * S + j) * 4 + w] = sbits;
    }

    // compact active lists: wave w handles rows i = w*32 .. w*32+31
    {
        int wave = t >> 6, lane = t & 63;
        for (int r = 0; r < 32; ++r) {
            int i = wave * 32 + r;
            unsigned char* dst = actg + (long long)(b * S + i) * S;
            bool a0 = mb[i * MB_STRIDE + lane] != 0;
            unsigned long long b0 = __ballot(a0);
            int n0 = __popcll(b0);
            if (a0) dst[__popcll(b0 & ((1ull << lane) - 1ull))] = (unsigned char)lane;
            bool a1 = mb[i * MB_STRIDE + 64 + lane] != 0;
            unsigned long long b1 = __ballot(a1);
            if (a1) dst[n0 + __popcll(b1 & ((1ull << lane) - 1ull))] = (unsigned char)(64 + lane);
            if (lane == 0) nactg[b * S + i] = n0 + __popcll(b1);
        }
    }
}

// -------- main: one block per (b,i); 3 barriers; shfl-tree reduce; dbuf prow --------
__global__ __launch_bounds__(256, 4) void mfvi_main(
    const float* __restrict__ s_span,
    const float* __restrict__ s_pair,
    const int* __restrict__ mask,
    const unsigned* __restrict__ spanw,
    const unsigned char* __restrict__ actg,
    const int* __restrict__ nactg,
    float* __restrict__ out)
{
    __shared__ unsigned      sw_l[S * 4];   // 2048 B
    __shared__ float         prow2[2][S];   // double-buffered sigmoid(q)
    __shared__ float         qsv [S];
    __shared__ unsigned char act_l[S];

    const int t  = threadIdx.x;
    const int bi = blockIdx.x;        // b*128 + i
    const int i  = bi & (S - 1);
    const int b  = bi >> 7;
    const int row0 = t >> 5;          // 0..7  (compact-row group = half-wave id)
    const int c4   = (t & 31) * 4;    // k base 0..124
    const float* tile = s_pair + (long long)bi * (S * S);
    const int nact = nactg[bi];

    // ---- init (single barrier) ----
    if (t < S) {
        act_l[t] = actg[(long long)bi * S + t];
        *(uint4*)&sw_l[t * 4] = *(const uint4*)&spanw[(b * S + t) * 4];
        float sv = s_span[(long long)bi * S + t];
        qsv[t] = sv;
        float p0 = fsig(sv);
        prow2[0][t] = p0;             // it-0 p for every row
        prow2[1][t] = p0;             // inactive rows keep this forever
        if (!mask[(long long)bi * S + t])
            out[(long long)bi * S + t] = p0;   // inactive: q == s_span forever
    }
    __syncthreads();

    // ---- load active rows into registers; apply span & k!=lo/hi masks ----
    float4 v[16];
    #pragma unroll
    for (int s = 0; s < 16; ++s) {
        int idx = row0 + 8 * s;
        if (idx < nact) {
            int j = act_l[idx];
            float4 x = *(const float4*)(tile + j * S + c4);
            unsigned cw = sw_l[j * 4 + (c4 >> 5)];
            int lo = i < j ? i : j, hi = i < j ? j : i;
            if ((lo >> 5) == (c4 >> 5)) cw &= ~(1u << (lo & 31));
            if ((hi >> 5) == (c4 >> 5)) cw &= ~(1u << (hi & 31));
            unsigned cs = cw >> (c4 & 31);
            x.x = __int_as_float(__float_as_int(x.x) & (((int)(cs << 31)) >> 31));
            x.y = __int_as_float(__float_as_int(x.y) & (((int)(cs << 30)) >> 31));
            x.z = __int_as_float(__float_as_int(x.z) & (((int)(cs << 29)) >> 31));
            x.w = __int_as_float(__float_as_int(x.w) & (((int)(cs << 28)) >> 31));
            v[s] = x;
        } else {
            v[s] = make_float4(0.f, 0.f, 0.f, 0.f);
        }
    }

    // ---- 3 MFVI iterations; read buf it&1, write buf (it+1)&1 ----
    #pragma unroll
    for (int it = 0; it < 3; ++it) {
        const float* pr = prow2[it & 1];
        float*       pw = prow2[(it + 1) & 1];
        float4 p = *(const float4*)&pr[c4];     // 2-way broadcast read (free)
        float acc[16];
        #pragma unroll
        for (int s = 0; s < 16; ++s) {
            int idx = row0 + 8 * s;
            acc[s] = (idx < nact)
                   ? (v[s].x * p.x + v[s].y * p.y + v[s].z * p.z + v[s].w * p.w)
                   : 0.f;
        }
        #pragma unroll
        for (int s = 0; s < 16; ++s) {
            acc[s] += __shfl_xor(acc[s], 1);
            acc[s] += __shfl_xor(acc[s], 2);
            acc[s] += __shfl_xor(acc[s], 4);
            acc[s] += __shfl_xor(acc[s], 8);
            acc[s] += __shfl_xor(acc[s], 16);   // all 32 half-wave lanes hold row sum
        }
        if ((t & 31) == 0) {                     // one lane per half-wave commits 16 rows
            #pragma unroll
            for (int s = 0; s < 16; ++s) {
                int idx = row0 + 8 * s;
                if (idx < nact) {
                    int j = act_l[idx];
                    float q = qsv[j] + acc[s];
                    if (it < 2) pw[j] = fsig(q);
                    else        out[(long long)bi * S + j] = fsig(q);
                }
            }
        }
        if (it < 2) __syncthreads();
    }
}

extern "C" void kernel_launch(void* const* d_in, const int* in_sizes, int n_in,
                              void* d_out, int out_size, void* d_ws, size_t ws_size,
                              hipStream_t stream) {
    const float* s_span = (const float*)d_in[0];
    const float* s_pair = (const float*)d_in[1];
    const int*   mask   = (const int*)d_in[2];
    float*       out    = (float*)d_out;

    int num_rows = in_sizes[0] / S;        // B*S = 2048
    int B        = in_sizes[2] / (S * S);  // 16

    unsigned*      ws_span = (unsigned*)d_ws;                        // 32 KB
    unsigned char* ws_act  = (unsigned char*)(ws_span + (size_t)B * S * 4); // 256 KB
    int*           ws_nact = (int*)(ws_act + (size_t)B * S * S);     // 8 KB

    pack_masks<<<B, 256, 0, stream>>>(mask, ws_span, ws_act, ws_nact);
    mfvi_main<<<num_rows, 256, 0, stream>>>(s_span, s_pair, mask,
                                            ws_span, ws_act, ws_nact, out);
}

// Round 6
// 198.987 us; speedup vs baseline: 1.0697x; 1.0697x over previous
//
#include <hip/hip_runtime.h>
#include <hip/hip_bf16.h>

// MFVIConstituency: B=16, S=128, MAX_ITER=3.
// q_new[b,i,j] = s_span[b,i,j] + sum_k sigmoid(q[b,i,k]) * sp[b,i,j,k]
// sp[b,i,j,k]  = s_pair[b,i,j,k] * ( mask[b,i,j] & (k!=min(i,j)) & (k!=max(i,j))
//                                     & (mask[b,j,k]|mask[b,k,j]) )
//
// Round-6: merging-butterfly half-wave reduction (16 shuffles/iter vs 80 in
// round 5, vs ~48 LDS ops in round 3), 16-lane parallel commit, double-
// buffered prow (round-4 race fix), precomputed compact active lists.

#define S 128
#define MB_STRIDE 132     // mask byte tile: transposed byte reads conflict-free

static __device__ __forceinline__ float fsig(float x) {
    return __builtin_amdgcn_rcpf(1.0f + __expf(-x));
}

// -------- pre-pack per batch: span bitmasks + per-(b,i) compact row lists --------
__global__ __launch_bounds__(256, 2) void pack_masks(
    const int* __restrict__ mask,
    unsigned* __restrict__ spanw,        // [B*S*4]  bit k of row j: m[j,k]|m[k,j]
    unsigned char* __restrict__ actg,    // [B*S*S]  compact active-j list per (b,i)
    int* __restrict__ nactg)             // [B*S]
{
    __shared__ unsigned char mb[S * MB_STRIDE];   // 16896 B
    const int t = threadIdx.x, b = blockIdx.x;
    const int* mrow = mask + (long long)b * (S * S);
    #pragma unroll
    for (int s2 = 0; s2 < 16; ++s2) {
        int f4 = t + 256 * s2;            // int4 index 0..4095
        int j  = f4 >> 5;
        int k0 = (f4 & 31) * 4;
        int4 v = *(const int4*)(mrow + f4 * 4);
        unsigned packed = (v.x ? 1u : 0u)
                        | ((v.y ? 1u : 0u) << 8)
                        | ((v.z ? 1u : 0u) << 16)
                        | ((v.w ? 1u : 0u) << 24);
        *(unsigned*)(mb + j * MB_STRIDE + k0) = packed;
    }
    __syncthreads();

    // span bits
    #pragma unroll
    for (int r = 0; r < 2; ++r) {
        int task = t * 2 + r;             // (j, w)
        int j = task >> 2, w = task & 3;
        unsigned sbits = 0;
        #pragma unroll
        for (int c = 0; c < 32; ++c) {
            int k = w * 32 + c;
            sbits |= ((mb[j * MB_STRIDE + k] | mb[k * MB_STRIDE + j]) ? 1u : 0u) << c;
        }
        spanw[(b * S + j) * 4 + w] = sbits;
    }

    // compact active lists: wave w handles rows i = w*32 .. w*32+31
    {
        int wave = t >> 6, lane = t & 63;
        for (int r = 0; r < 32; ++r) {
            int i = wave * 32 + r;
            unsigned char* dst = actg + (long long)(b * S + i) * S;
            bool a0 = mb[i * MB_STRIDE + lane] != 0;
            unsigned long long b0 = __ballot(a0);
            int n0 = __popcll(b0);
            if (a0) dst[__popcll(b0 & ((1ull << lane) - 1ull))] = (unsigned char)lane;
            bool a1 = mb[i * MB_STRIDE + 64 + lane] != 0;
            unsigned long long b1 = __ballot(a1);
            if (a1) dst[n0 + __popcll(b1 & ((1ull << lane) - 1ull))] = (unsigned char)(64 + lane);
            if (lane == 0) nactg[b * S + i] = n0 + __popcll(b1);
        }
    }
}

// -------- main: one block per (b,i); 3 barriers; merging-butterfly reduce --------
__global__ __launch_bounds__(256, 4) void mfvi_main(
    const float* __restrict__ s_span,
    const float* __restrict__ s_pair,
    const int* __restrict__ mask,
    const unsigned* __restrict__ spanw,
    const unsigned char* __restrict__ actg,
    const int* __restrict__ nactg,
    float* __restrict__ out)
{
    __shared__ unsigned      sw_l[S * 4];   // 2048 B
    __shared__ float         prow2[2][S];   // double-buffered sigmoid(q)
    __shared__ float         qsv [S];
    __shared__ unsigned char act_l[S];

    const int t  = threadIdx.x;
    const int bi = blockIdx.x;        // b*128 + i
    const int i  = bi & (S - 1);
    const int b  = bi >> 7;
    const int row0 = t >> 5;          // 0..7  (half-wave id)
    const int L    = t & 31;          // lane within half-wave
    const int c4   = L * 4;           // k base 0..124
    const float* tile = s_pair + (long long)bi * (S * S);
    float* outrow = out + (long long)bi * S;
    const int nact = nactg[bi];

    // ---- init (single barrier) ----
    if (t < S) {
        act_l[t] = actg[(long long)bi * S + t];
        *(uint4*)&sw_l[t * 4] = *(const uint4*)&spanw[(b * S + t) * 4];
        float sv = s_span[(long long)bi * S + t];
        qsv[t] = sv;
        float p0 = fsig(sv);
        prow2[0][t] = p0;             // it-0 p for every row
        prow2[1][t] = p0;             // inactive rows keep this forever
        if (!mask[(long long)bi * S + t])
            outrow[t] = p0;           // inactive: q == s_span forever
    }
    __syncthreads();

    // ---- load active rows into registers; apply span & k!=lo/hi masks ----
    float4 v[16];
    #pragma unroll
    for (int s = 0; s < 16; ++s) {
        int idx = row0 + 8 * s;
        if (idx < nact) {
            int j = act_l[idx];
            float4 x = *(const float4*)(tile + j * S + c4);
            unsigned cw = sw_l[j * 4 + (c4 >> 5)];
            int lo = i < j ? i : j, hi = i < j ? j : i;
            if ((lo >> 5) == (c4 >> 5)) cw &= ~(1u << (lo & 31));
            if ((hi >> 5) == (c4 >> 5)) cw &= ~(1u << (hi & 31));
            unsigned cs = cw >> (c4 & 31);
            x.x = __int_as_float(__float_as_int(x.x) & (((int)(cs << 31)) >> 31));
            x.y = __int_as_float(__float_as_int(x.y) & (((int)(cs << 30)) >> 31));
            x.z = __int_as_float(__float_as_int(x.z) & (((int)(cs << 29)) >> 31));
            x.w = __int_as_float(__float_as_int(x.w) & (((int)(cs << 28)) >> 31));
            v[s] = x;
        } else {
            v[s] = make_float4(0.f, 0.f, 0.f, 0.f);
        }
    }

    // ---- 3 MFVI iterations; merging butterfly: lane L ends with row L&15 ----
    #pragma unroll
    for (int it = 0; it < 3; ++it) {
        const float* pr = prow2[it & 1];
        float*       pw = prow2[(it + 1) & 1];
        float4 p = *(const float4*)&pr[c4];     // 2-way broadcast read (free)
        float acc[16];
        #pragma unroll
        for (int s = 0; s < 16; ++s)            // dead rows: v[s]==0 -> acc 0
            acc[s] = v[s].x * p.x + v[s].y * p.y + v[s].z * p.z + v[s].w * p.w;

        // 16 -> 8 -> 4 -> 2 -> 1 values, lane bit n selects s bit n
        #pragma unroll
        for (int m = 0; m < 8; ++m) {
            float a = acc[2 * m], bb = acc[2 * m + 1];
            float sent = (L & 1) ? a : bb;
            float keep = (L & 1) ? bb : a;
            acc[m] = keep + __shfl_xor(sent, 1);
        }
        #pragma unroll
        for (int m = 0; m < 4; ++m) {
            float a = acc[2 * m], bb = acc[2 * m + 1];
            float sent = (L & 2) ? a : bb;
            float keep = (L & 2) ? bb : a;
            acc[m] = keep + __shfl_xor(sent, 2);
        }
        #pragma unroll
        for (int m = 0; m < 2; ++m) {
            float a = acc[2 * m], bb = acc[2 * m + 1];
            float sent = (L & 4) ? a : bb;
            float keep = (L & 4) ? bb : a;
            acc[m] = keep + __shfl_xor(sent, 4);
        }
        float r;
        {
            float a = acc[0], bb = acc[1];
            float sent = (L & 8) ? a : bb;
            float keep = (L & 8) ? bb : a;
            r = keep + __shfl_xor(sent, 8);
        }
        r += __shfl_xor(r, 16);                 // full 32-lane row sum

        if (L < 16) {                            // 16 parallel commits per half-wave
            int idx = row0 + 8 * L;
            if (idx < nact) {
                int j = act_l[idx];
                float q = qsv[j] + r;
                if (it < 2) pw[j] = fsig(q);
                else        outrow[j] = fsig(q);
            }
        }
        if (it < 2) __syncthreads();
    }
}

extern "C" void kernel_launch(void* const* d_in, const int* in_sizes, int n_in,
                              void* d_out, int out_size, void* d_ws, size_t ws_size,
                              hipStream_t stream) {
    const float* s_span = (const float*)d_in[0];
    const float* s_pair = (const float*)d_in[1];
    const int*   mask   = (const int*)d_in[2];
    float*       out    = (float*)d_out;

    int num_rows = in_sizes[0] / S;        // B*S = 2048
    int B        = in_sizes[2] / (S * S);  // 16

    unsigned*      ws_span = (unsigned*)d_ws;                        // 32 KB
    unsigned char* ws_act  = (unsigned char*)(ws_span + (size_t)B * S * 4); // 256 KB
    int*           ws_nact = (int*)(ws_act + (size_t)B * S * S);     // 8 KB

    pack_masks<<<B, 256, 0, stream>>>(mask, ws_span, ws_act, ws_nact);
    mfvi_main<<<num_rows, 256, 0, stream>>>(s_span, s_pair, mask,
                                            ws_span, ws_act, ws_nact, out);
}